// Round 1
// 278.730 us; speedup vs baseline: 1.2847x; 1.2847x over previous
//
#include <hip/hip_runtime.h>
#include <hip/hip_bf16.h>

typedef __attribute__((ext_vector_type(4))) float floatx4;
typedef __attribute__((ext_vector_type(8))) short shortx8;

#define NB   16
#define CIN  256
#define COUT 256
#define KW   3
#define LL   4096
#define NR   5
#define QK   768    // CIN*KW
#define NP   65536  // NB*LL

static __device__ __forceinline__ unsigned short bf16bits(float f) {
    __hip_bfloat16 h = __float2bfloat16(f);
    return __builtin_bit_cast(unsigned short, h);
}

// async global->LDS, 16B per lane, LDS dest = wave-uniform base + lane*16
static __device__ __forceinline__ void gload16(const void* g, void* l) {
    __builtin_amdgcn_global_load_lds(
        (const __attribute__((address_space(1))) void*)g,
        (__attribute__((address_space(3))) void*)l, 16, 0, 0);
}

// ---------------- K0a: transpose x (B,Cin,L) fp32 -> xt (B,L,Cin) bf16 ----------------
__global__ void k_transpose(const float* __restrict__ x, __hip_bfloat16* __restrict__ xt) {
    __shared__ float t[64][65];
    int l0 = blockIdx.x * 64, c0 = blockIdx.y * 64, b = blockIdx.z;
    int tid = threadIdx.x;
    int r16 = tid >> 4, q16 = tid & 15;
    #pragma unroll
    for (int pass = 0; pass < 4; ++pass) {
        int cin = pass * 16 + r16;
        float4 v = *(const float4*)&x[((size_t)(b * CIN + c0 + cin)) * LL + l0 + q16 * 4];
        t[q16 * 4 + 0][cin] = v.x;
        t[q16 * 4 + 1][cin] = v.y;
        t[q16 * 4 + 2][cin] = v.z;
        t[q16 * 4 + 3][cin] = v.w;
    }
    __syncthreads();
    #pragma unroll
    for (int pass = 0; pass < 4; ++pass) {
        int lr = pass * 16 + r16;
        int c4 = q16 * 4;
        ushort4 u;
        u.x = bf16bits(t[lr][c4 + 0]);
        u.y = bf16bits(t[lr][c4 + 1]);
        u.z = bf16bits(t[lr][c4 + 2]);
        u.w = bf16bits(t[lr][c4 + 3]);
        *(ushort4*)&xt[((size_t)(b * LL + l0 + lr)) * CIN + c0 + c4] = u;
    }
}

// ---------------- K0b: weights -> bf16, M-order m = (o>>4)*80 + r*16 + (o&15), q' = k*256+cin ----------------
__global__ void k_wprep(const float* __restrict__ bk, __hip_bfloat16* __restrict__ wb) {
    int i = blockIdx.x * 256 + threadIdx.x;
    if (i >= NR * COUT * QK) return;
    int m = i / QK, q = i % QK;
    int o = (m / 80) * 16 + (m & 15);
    int r = (m % 80) / 16;
    int k = q >> 8, cin = q & 255;
    wb[i] = __float2bfloat16(bk[((r * COUT + o) * CIN + cin) * KW + k]);
}

// ---------------- K1: controller -> fr (P,5) fp32 ----------------
__global__ void k_fr(const float* __restrict__ x, const float* __restrict__ cw,
                     const float* __restrict__ cb, float* __restrict__ fr) {
    __shared__ float xsh[128][68];     // 34816 B
    __shared__ float cws[QK * NR];     // 15360 B
    __shared__ float part[4][64][NR];  // 5120 B
    int p0 = blockIdx.x * 64;
    int b = p0 >> 12, l0 = p0 & (LL - 1);
    int tid = threadIdx.x, lane = tid & 63, wid = tid >> 6;
    for (int i = tid; i < QK * NR; i += 256) cws[i] = cw[i];
    float lg[NR] = {0.f, 0.f, 0.f, 0.f, 0.f};
    for (int ch = 0; ch < 2; ++ch) {
        __syncthreads();
        for (int i = tid; i < 128 * 17; i += 256) {
            int cl = i / 17, c4 = (i % 17) * 4;
            int gl = l0 - 4 + c4;
            float4 v = make_float4(0.f, 0.f, 0.f, 0.f);
            if (gl >= 0) v = *(const float4*)&x[((size_t)(b * CIN + ch * 128 + cl)) * LL + gl];
            *(float4*)&xsh[cl][c4] = v;
        }
        __syncthreads();
        #pragma unroll 8
        for (int r = 0; r < 32; ++r) {
            int cl = wid * 32 + r;
            int cg = ch * 128 + cl;
            float x0 = xsh[cl][lane + 2], x1 = xsh[cl][lane + 3], x2 = xsh[cl][lane + 4];
            const float* w = &cws[cg * 3 * NR];
            #pragma unroll
            for (int n = 0; n < NR; ++n)
                lg[n] += x0 * w[n] + x1 * w[NR + n] + x2 * w[2 * NR + n];
        }
    }
    #pragma unroll
    for (int n = 0; n < NR; ++n) part[wid][lane][n] = lg[n];
    __syncthreads();
    if (tid < 64) {
        float l2[NR];
        #pragma unroll
        for (int n = 0; n < NR; ++n)
            l2[n] = cb[n] + part[0][tid][n] + part[1][tid][n] + part[2][tid][n] + part[3][tid][n];
        float m = l2[0];
        #pragma unroll
        for (int n = 1; n < NR; ++n) m = fmaxf(m, l2[n]);
        float e[NR], s = 0.f;
        #pragma unroll
        for (int n = 0; n < NR; ++n) { e[n] = __expf(l2[n] - m); s += e[n]; }
        float inv = 1.f / s;
        #pragma unroll
        for (int n = 0; n < NR; ++n) fr[(size_t)(p0 + tid) * NR + n] = e[n] * inv;
    }
}

// ---------------- K2: fused conv + mixture, gload_lds double-buffered 8-phase pipeline ----------------
// GEMM M=1280, N=65536, K=768. Block M=80 x N=256, 4 waves each 80x64.
// 8 K-phases of 32 cins x 3 kh. Per-buffer LDS: X = 258 rows x 32 cins (halo rows 0,1)
// + W = 240 strips x 32 cins. Double-buffered; staging via global_load_lds width=16
// (pre-swizzled global source, linear LDS dest) -> zero staging VGPRs, no scratch spill.
// 2-bit XOR swizzle (chunk = quad ^ (row&3)) -> conflict-free ds_read_b128.
#define BUFSH 15936   // shorts per buffer: 258*32 + 240*32
#define WOFFS 8256    // short offset of W region (258*32)
__global__ __launch_bounds__(256, 2)
void k_conv(const __hip_bfloat16* __restrict__ xt, const __hip_bfloat16* __restrict__ wb,
            const float* __restrict__ fr, const float* __restrict__ bias,
            float* __restrict__ out) {
    __shared__ __align__(16) short lds[2 * BUFSH];  // 63744 B
    __shared__ float bs[80];                        // 320 B

    int g = blockIdx.x;
    int pt = ((g >> 7) << 3) | (g & 7);   // XCD swizzle: same pt -> same XCD (mod-8)
    int y  = (g >> 3) & 15;
    int p0 = pt * 256;
    int m0 = y * 80, o0 = y * 16;
    int b = p0 >> 12, l0 = p0 & (LL - 1);
    int tid = threadIdx.x;
    int lane = tid & 63, wn = tid >> 6;
    int quad = lane >> 4, l16 = lane & 15;

    const __hip_bfloat16* xb = xt + (size_t)b * (LL * CIN);

    if (tid < 80) bs[tid] = bias[(tid >> 4) * COUT + o0 + (tid & 15)];

    // ---- per-thread phase-0 global source offsets (elements); phase adds +32 ----
    int xsrc[4];
    #pragma unroll
    for (int j = 0; j < 4; ++j) {
        int i = tid + j * 256;                 // main X chunk 0..1023
        int rowp = i >> 2, cslot = i & 3;
        int cg = cslot ^ ((rowp + 2) & 3);     // LDS row = rowp+2
        xsrc[j] = (l0 + rowp) * CIN + cg * 8;
    }
    int wsrc[4];
    #pragma unroll
    for (int j = 0; j < 4; ++j) {
        int i = tid + j * 256;                 // W chunk 0..959 (j=3: waves 0..2 only)
        int s = i >> 2, cslot = i & 3;
        int cg = cslot ^ (s & 3);
        int kh = s / 80, m = s - kh * 80;
        wsrc[j] = (i < 960) ? ((m0 + m) * QK + kh * 256 + cg * 8) : 0;
    }
    // halo rows 0,1 (gl = l0-2, l0-1): 8 chunks, reg->ds_write path
    int hR = tid >> 2, hslot = tid & 3;
    int hcg = hslot ^ (hR & 3);
    int hsrc = (l0 - 2 + hR) * CIN + hcg * 8;  // only used when l0>0 && tid<8

    // ---- LDS fragment read offsets (short idx within one buffer) ----
    int boff[3][4], aoff[3][5];
    #pragma unroll
    for (int kh = 0; kh < 3; ++kh) {
        #pragma unroll
        for (int nf = 0; nf < 4; ++nf) {
            int row = wn * 64 + nf * 16 + l16 + kh;
            int phys = quad ^ (row & 3);
            boff[kh][nf] = row * 32 + phys * 8;
        }
        #pragma unroll
        for (int mf = 0; mf < NR; ++mf) {
            int s = kh * 80 + mf * 16 + l16;
            int phys = quad ^ (s & 3);
            aoff[kh][mf] = WOFFS + s * 32 + phys * 8;
        }
    }

    floatx4 acc[NR][4];
    #pragma unroll
    for (int mf = 0; mf < NR; ++mf)
        #pragma unroll
        for (int nf = 0; nf < 4; ++nf)
            acc[mf][nf] = (floatx4){0.f, 0.f, 0.f, 0.f};

    auto stage = [&](short* B, int ph) {
        const __hip_bfloat16* xp = xb + ph * 32;
        const __hip_bfloat16* wp = wb + ph * 32;
        uint4 hv = make_uint4(0u, 0u, 0u, 0u);
        if (l0 > 0 && tid < 8) hv = *(const uint4*)(xp + hsrc);
        #pragma unroll
        for (int j = 0; j < 4; ++j)
            gload16(xp + xsrc[j], B + 64 + (j * 256 + wn * 64) * 8);
        #pragma unroll
        for (int j = 0; j < 3; ++j)
            gload16(wp + wsrc[j], B + WOFFS + (j * 256 + wn * 64) * 8);
        if (wn < 3)
            gload16(wp + wsrc[3], B + WOFFS + (768 + wn * 64) * 8);
        if (tid < 8) *(uint4*)(B + tid * 8) = hv;   // halo (zeros when l0==0)
    };

    auto compute = [&](const short* B) {
        #pragma unroll
        for (int kh = 0; kh < 3; ++kh) {
            shortx8 bfrag[4], afrag[NR];
            #pragma unroll
            for (int nf = 0; nf < 4; ++nf)
                bfrag[nf] = *(const shortx8*)&B[boff[kh][nf]];
            #pragma unroll
            for (int mf = 0; mf < NR; ++mf)
                afrag[mf] = *(const shortx8*)&B[aoff[kh][mf]];
            #pragma unroll
            for (int mf = 0; mf < NR; ++mf)
                #pragma unroll
                for (int nf = 0; nf < 4; ++nf)
                    acc[mf][nf] = __builtin_amdgcn_mfma_f32_16x16x32_bf16(
                        afrag[mf], bfrag[nf], acc[mf][nf], 0, 0, 0);
        }
    };

    stage(&lds[0], 0);
    __syncthreads();                       // drains vmcnt(0): buf0 ready
    for (int ph = 0; ph < 8; ph += 2) {
        stage(&lds[BUFSH], ph + 1);        // issue next-phase loads (in flight over compute)
        compute(&lds[0]);
        __syncthreads();                   // vmcnt(0)+lgkmcnt(0): buf1 ready, buf0 free
        if (ph < 6) stage(&lds[0], ph + 2);
        compute(&lds[BUFSH]);
        __syncthreads();
    }

    // ---- epilogue: out[b, o0+olo, l0+colp] = sum_r fr[p][r]*(acc[r] + bias[r][o]) ----
    #pragma unroll
    for (int nf = 0; nf < 4; ++nf) {
        int colp = wn * 64 + nf * 16 + l16;
        const float* fp = fr + (size_t)(p0 + colp) * NR;
        float f0 = fp[0], f1 = fp[1], f2 = fp[2], f3 = fp[3], f4 = fp[4];
        #pragma unroll
        for (int j = 0; j < 4; ++j) {
            int olo = quad * 4 + j;
            float v = f0 * (acc[0][nf][j] + bs[0 * 16 + olo])
                    + f1 * (acc[1][nf][j] + bs[1 * 16 + olo])
                    + f2 * (acc[2][nf][j] + bs[2 * 16 + olo])
                    + f3 * (acc[3][nf][j] + bs[3 * 16 + olo])
                    + f4 * (acc[4][nf][j] + bs[4 * 16 + olo]);
            out[((size_t)(b * COUT + o0 + olo)) * LL + l0 + colp] = v;
        }
    }
}

extern "C" void kernel_launch(void* const* d_in, const int* in_sizes, int n_in,
                              void* d_out, int out_size, void* d_ws, size_t ws_size,
                              hipStream_t stream) {
    const float* x  = (const float*)d_in[0];
    const float* bk = (const float*)d_in[1];
    const float* bb = (const float*)d_in[2];
    const float* cw = (const float*)d_in[3];
    const float* cb = (const float*)d_in[4];
    float* out = (float*)d_out;

    char* ws = (char*)d_ws;
    __hip_bfloat16* xt = (__hip_bfloat16*)ws;                         // 33,554,432 B
    __hip_bfloat16* wb = (__hip_bfloat16*)(ws + 33554432);            //  1,966,080 B
    float*          fr = (float*)(ws + 33554432 + 1966080);           //  1,310,720 B

    k_transpose<<<dim3(LL / 64, CIN / 64, NB), dim3(256), 0, stream>>>(x, xt);
    k_wprep<<<dim3((NR * COUT * QK + 255) / 256), dim3(256), 0, stream>>>(bk, wb);
    k_fr<<<dim3(NP / 64), dim3(256), 0, stream>>>(x, cw, cb, fr);
    k_conv<<<dim3(NP / 256 * (COUT / 16)), dim3(256), 0, stream>>>(xt, wb, fr, bb, out);
}

// Round 2
// 264.364 us; speedup vs baseline: 1.3546x; 1.0543x over previous
//
#include <hip/hip_runtime.h>
#include <hip/hip_bf16.h>

typedef __attribute__((ext_vector_type(4))) float floatx4;
typedef __attribute__((ext_vector_type(8))) short shortx8;

#define NB   16
#define CIN  256
#define COUT 256
#define KW   3
#define LL   4096
#define NR   5
#define QK   768    // CIN*KW
#define NP   65536  // NB*LL

static __device__ __forceinline__ unsigned short bf16bits(float f) {
    __hip_bfloat16 h = __float2bfloat16(f);
    return __builtin_bit_cast(unsigned short, h);
}

// async global->LDS, 16B per lane, LDS dest = wave-uniform base + lane*16
static __device__ __forceinline__ void gload16(const void* g, void* l) {
    __builtin_amdgcn_global_load_lds(
        (const __attribute__((address_space(1))) void*)g,
        (__attribute__((address_space(3))) void*)l, 16, 0, 0);
}

// ---------------- K0b: weights -> bf16 + zero the logits/fr buffer ----------------
__global__ void k_wprep(const float* __restrict__ bk, __hip_bfloat16* __restrict__ wb,
                        float* __restrict__ frz) {
    int i = blockIdx.x * 256 + threadIdx.x;
    if (i < NP * NR) frz[i] = 0.f;
    if (i >= NR * COUT * QK) return;
    int m = i / QK, q = i % QK;
    int o = (m / 80) * 16 + (m & 15);
    int r = (m % 80) / 16;
    int k = q >> 8, cin = q & 255;
    wb[i] = __float2bfloat16(bk[((r * COUT + o) * CIN + cin) * KW + k]);
}

// ---------------- K1: fused transpose + controller partial logits ----------------
// Each block: 64 l x 64 cin tile of x. (a) transpose -> xt bf16, (b) partial
// logits over its 64 cins (fp32, exact), atomicAdd into fr buffer (pre-zeroed).
__global__ void k_tfr(const float* __restrict__ x, const float* __restrict__ cw,
                      __hip_bfloat16* __restrict__ xt, float* __restrict__ logit) {
    __shared__ float t[66][65];        // row = l_local+2 (halo rows 0,1), col = cin
    __shared__ float cwsh[64 * 15];    // cw slice for this cin group
    int l0 = blockIdx.x * 64, c0 = blockIdx.y * 64, b = blockIdx.z;
    int tid = threadIdx.x;
    int r16 = tid >> 4, q16 = tid & 15;

    for (int i = tid; i < 64 * 15; i += 256) cwsh[i] = cw[c0 * 15 + i];

    #pragma unroll
    for (int pass = 0; pass < 4; ++pass) {
        int cin = pass * 16 + r16;
        float4 v = *(const float4*)&x[((size_t)(b * CIN + c0 + cin)) * LL + l0 + q16 * 4];
        t[q16 * 4 + 2][cin] = v.x;
        t[q16 * 4 + 3][cin] = v.y;
        t[q16 * 4 + 4][cin] = v.z;
        t[q16 * 4 + 5][cin] = v.w;
    }
    if (tid < 128) {  // halo columns l0-2, l0-1 (zeros at l0==0: causal pad)
        int cin = tid >> 1, j = tid & 1;
        float v = 0.f;
        if (l0 > 0) v = x[((size_t)(b * CIN + c0 + cin)) * LL + l0 - 2 + j];
        t[j][cin] = v;
    }
    __syncthreads();

    // transpose write: xt[b, l, cin] bf16
    #pragma unroll
    for (int pass = 0; pass < 4; ++pass) {
        int lr = pass * 16 + r16;
        int c4 = q16 * 4;
        ushort4 u;
        u.x = bf16bits(t[lr + 2][c4 + 0]);
        u.y = bf16bits(t[lr + 2][c4 + 1]);
        u.z = bf16bits(t[lr + 2][c4 + 2]);
        u.w = bf16bits(t[lr + 2][c4 + 3]);
        *(ushort4*)&xt[((size_t)(b * LL + l0 + lr)) * CIN + c0 + c4] = u;
    }

    // controller partials: 4 threads per position, 16 cins each
    int p = tid >> 2, q = tid & 3;
    float lg[NR] = {0.f, 0.f, 0.f, 0.f, 0.f};
    #pragma unroll 4
    for (int ci = 0; ci < 16; ++ci) {
        int cin = q * 16 + ci;
        float x0 = t[p][cin], x1 = t[p + 1][cin], x2 = t[p + 2][cin];
        const float* w = &cwsh[cin * 15];
        #pragma unroll
        for (int n = 0; n < NR; ++n)
            lg[n] += x0 * w[n] + x1 * w[5 + n] + x2 * w[10 + n];
    }
    #pragma unroll
    for (int n = 0; n < NR; ++n) {
        lg[n] += __shfl_xor(lg[n], 1);
        lg[n] += __shfl_xor(lg[n], 2);
    }
    if (q == 0) {
        float* lp = &logit[(size_t)(b * LL + l0 + p) * NR];
        #pragma unroll
        for (int n = 0; n < NR; ++n) atomicAdd(&lp[n], lg[n]);
    }
}

// ---------------- K1b: softmax in-place on fr buffer ----------------
__global__ void k_softmax(const float* __restrict__ cb, float* __restrict__ fr) {
    int p = blockIdx.x * 256 + threadIdx.x;
    if (p >= NP) return;
    float l2[NR];
    #pragma unroll
    for (int n = 0; n < NR; ++n) l2[n] = fr[(size_t)p * NR + n] + cb[n];
    float m = l2[0];
    #pragma unroll
    for (int n = 1; n < NR; ++n) m = fmaxf(m, l2[n]);
    float e[NR], s = 0.f;
    #pragma unroll
    for (int n = 0; n < NR; ++n) { e[n] = __expf(l2[n] - m); s += e[n]; }
    float inv = 1.f / s;
    #pragma unroll
    for (int n = 0; n < NR; ++n) fr[(size_t)p * NR + n] = e[n] * inv;
}

// ---------------- K2: fused conv + mixture, gload_lds double-buffered 8-phase pipeline ----------------
// GEMM M=1280, N=65536, K=768. Block M=80 x N=256, 4 waves each 80x64.
// 8 K-phases of 32 cins x 3 kh. Per-buffer LDS: X = 258 rows x 32 cins (halo rows 0,1)
// + W = 240 strips x 32 cins. Double-buffered; staging via global_load_lds width=16
// (pre-swizzled global source, linear LDS dest).
// Swizzle f(row) = (row>>1)&3: with 64B rows, bank = 16*(row&1) + 4*(quad^f(row));
// over 16 consecutive rows (row&1, f) covers all 8 combos -> 8 bank-groups x 2 lanes
// = b128 minimum (the round-1 f=row&3 aliased row&1 with f -> 2x conflicts).
#define BUFSH 15936   // shorts per buffer: 258*32 + 240*32
#define WOFFS 8256    // short offset of W region (258*32)
__global__ __launch_bounds__(256, 2)
void k_conv(const __hip_bfloat16* __restrict__ xt, const __hip_bfloat16* __restrict__ wb,
            const float* __restrict__ fr, const float* __restrict__ bias,
            float* __restrict__ out) {
    __shared__ __align__(16) short lds[2 * BUFSH];  // 63744 B
    __shared__ float bs[80];                        // 320 B

    int g = blockIdx.x;
    int pt = ((g >> 7) << 3) | (g & 7);   // XCD swizzle: same pt -> same XCD (mod-8)
    int y  = (g >> 3) & 15;
    int p0 = pt * 256;
    int m0 = y * 80, o0 = y * 16;
    int b = p0 >> 12, l0 = p0 & (LL - 1);
    int tid = threadIdx.x;
    int lane = tid & 63, wn = tid >> 6;
    int quad = lane >> 4, l16 = lane & 15;

    const __hip_bfloat16* xb = xt + (size_t)b * (LL * CIN);

    if (tid < 80) bs[tid] = bias[(tid >> 4) * COUT + o0 + (tid & 15)];

    // ---- per-thread phase-0 global source offsets (elements); phase adds +32 ----
    int xsrc[4];
    #pragma unroll
    for (int j = 0; j < 4; ++j) {
        int i = tid + j * 256;                 // main X chunk 0..1023
        int rowp = i >> 2, cslot = i & 3;
        int cg = cslot ^ (((rowp + 2) >> 1) & 3);   // LDS row = rowp+2
        xsrc[j] = (l0 + rowp) * CIN + cg * 8;
    }
    int wsrc[4];
    #pragma unroll
    for (int j = 0; j < 4; ++j) {
        int i = tid + j * 256;                 // W chunk 0..959 (j=3: waves 0..2 only)
        int s = i >> 2, cslot = i & 3;
        int cg = cslot ^ ((s >> 1) & 3);
        int kh = s / 80, m = s - kh * 80;
        wsrc[j] = (i < 960) ? ((m0 + m) * QK + kh * 256 + cg * 8) : 0;
    }
    // halo rows 0,1 (gl = l0-2, l0-1): 8 chunks, reg->ds_write path. f(0)=f(1)=0.
    int hR = tid >> 2, hslot = tid & 3;
    int hcg = hslot;
    int hsrc = (l0 - 2 + hR) * CIN + hcg * 8;  // only used when l0>0 && tid<8

    // ---- LDS fragment read offsets (short idx within one buffer) ----
    int boff[3][4], aoff[3][5];
    #pragma unroll
    for (int kh = 0; kh < 3; ++kh) {
        #pragma unroll
        for (int nf = 0; nf < 4; ++nf) {
            int row = wn * 64 + nf * 16 + l16 + kh;
            int phys = quad ^ ((row >> 1) & 3);
            boff[kh][nf] = row * 32 + phys * 8;
        }
        #pragma unroll
        for (int mf = 0; mf < NR; ++mf) {
            int s = kh * 80 + mf * 16 + l16;
            int phys = quad ^ ((s >> 1) & 3);
            aoff[kh][mf] = WOFFS + s * 32 + phys * 8;
        }
    }

    floatx4 acc[NR][4];
    #pragma unroll
    for (int mf = 0; mf < NR; ++mf)
        #pragma unroll
        for (int nf = 0; nf < 4; ++nf)
            acc[mf][nf] = (floatx4){0.f, 0.f, 0.f, 0.f};

    auto stage = [&](short* B, int ph) {
        const __hip_bfloat16* xp = xb + ph * 32;
        const __hip_bfloat16* wp = wb + ph * 32;
        uint4 hv = make_uint4(0u, 0u, 0u, 0u);
        if (l0 > 0 && tid < 8) hv = *(const uint4*)(xp + hsrc);
        #pragma unroll
        for (int j = 0; j < 4; ++j)
            gload16(xp + xsrc[j], B + 64 + (j * 256 + wn * 64) * 8);
        #pragma unroll
        for (int j = 0; j < 3; ++j)
            gload16(wp + wsrc[j], B + WOFFS + (j * 256 + wn * 64) * 8);
        if (wn < 3)
            gload16(wp + wsrc[3], B + WOFFS + (768 + wn * 64) * 8);
        if (tid < 8) *(uint4*)(B + tid * 8) = hv;   // halo (zeros when l0==0)
    };

    auto compute = [&](const short* B) {
        #pragma unroll
        for (int kh = 0; kh < 3; ++kh) {
            shortx8 bfrag[4], afrag[NR];
            #pragma unroll
            for (int nf = 0; nf < 4; ++nf)
                bfrag[nf] = *(const shortx8*)&B[boff[kh][nf]];
            #pragma unroll
            for (int mf = 0; mf < NR; ++mf)
                afrag[mf] = *(const shortx8*)&B[aoff[kh][mf]];
            #pragma unroll
            for (int mf = 0; mf < NR; ++mf)
                #pragma unroll
                for (int nf = 0; nf < 4; ++nf)
                    acc[mf][nf] = __builtin_amdgcn_mfma_f32_16x16x32_bf16(
                        afrag[mf], bfrag[nf], acc[mf][nf], 0, 0, 0);
        }
    };

    stage(&lds[0], 0);
    __syncthreads();                       // drains vmcnt(0): buf0 ready
    for (int ph = 0; ph < 8; ph += 2) {
        stage(&lds[BUFSH], ph + 1);        // issue next-phase loads (in flight over compute)
        compute(&lds[0]);
        __syncthreads();                   // vmcnt(0)+lgkmcnt(0): buf1 ready, buf0 free
        if (ph < 6) stage(&lds[0], ph + 2);
        compute(&lds[BUFSH]);
        __syncthreads();
    }

    // ---- epilogue: out[b, o0+olo, l0+colp] = sum_r fr[p][r]*(acc[r] + bias[r][o]) ----
    #pragma unroll
    for (int nf = 0; nf < 4; ++nf) {
        int colp = wn * 64 + nf * 16 + l16;
        const float* fp = fr + (size_t)(p0 + colp) * NR;
        float f0 = fp[0], f1 = fp[1], f2 = fp[2], f3 = fp[3], f4 = fp[4];
        #pragma unroll
        for (int j = 0; j < 4; ++j) {
            int olo = quad * 4 + j;
            float v = f0 * (acc[0][nf][j] + bs[0 * 16 + olo])
                    + f1 * (acc[1][nf][j] + bs[1 * 16 + olo])
                    + f2 * (acc[2][nf][j] + bs[2 * 16 + olo])
                    + f3 * (acc[3][nf][j] + bs[3 * 16 + olo])
                    + f4 * (acc[4][nf][j] + bs[4 * 16 + olo]);
            out[((size_t)(b * COUT + o0 + olo)) * LL + l0 + colp] = v;
        }
    }
}

extern "C" void kernel_launch(void* const* d_in, const int* in_sizes, int n_in,
                              void* d_out, int out_size, void* d_ws, size_t ws_size,
                              hipStream_t stream) {
    const float* x  = (const float*)d_in[0];
    const float* bk = (const float*)d_in[1];
    const float* bb = (const float*)d_in[2];
    const float* cw = (const float*)d_in[3];
    const float* cb = (const float*)d_in[4];
    float* out = (float*)d_out;

    char* ws = (char*)d_ws;
    __hip_bfloat16* xt = (__hip_bfloat16*)ws;                         // 33,554,432 B
    __hip_bfloat16* wb = (__hip_bfloat16*)(ws + 33554432);            //  1,966,080 B
    float*          fr = (float*)(ws + 33554432 + 1966080);           //  1,310,720 B

    k_wprep<<<dim3((NR * COUT * QK + 255) / 256), dim3(256), 0, stream>>>(bk, wb, fr);
    k_tfr<<<dim3(LL / 64, CIN / 64, NB), dim3(256), 0, stream>>>(x, cw, xt, fr);
    k_softmax<<<dim3(NP / 256), dim3(256), 0, stream>>>(cb, fr);
    k_conv<<<dim3(NP / 256 * (COUT / 16)), dim3(256), 0, stream>>>(xt, wb, fr, bb, out);
}